// Round 1
// baseline (345.409 us; speedup 1.0000x reference)
//
#include <hip/hip_runtime.h>

// SAM ViT-B global attention, MI355X bf16-MFMA implementation.
// Pipeline: cvt(x,Wqkv,Wproj) -> QKV GEMM (scatter q,k,[V^T]) -> rel_h/rel_w
//           -> flash attention with decomposed rel-pos bias -> proj GEMM.
// Workspace budget ~61.4 MB.

typedef __bf16 bf16;
typedef __bf16 bf16x8 __attribute__((ext_vector_type(8)));
typedef float f32x4 __attribute__((ext_vector_type(4)));

__device__ __forceinline__ f32x4 mfma16(bf16x8 a, bf16x8 b, f32x4 c) {
  return __builtin_amdgcn_mfma_f32_16x16x32_bf16(a, b, c, 0, 0, 0);
}

typedef const __attribute__((address_space(1))) void* gas_ptr;
typedef __attribute__((address_space(3))) void* las_ptr;
__device__ __forceinline__ void gl_lds16(const void* g, void* l) {
  // async global->LDS, 16B/lane; LDS dest is wave-uniform base + lane*16
  __builtin_amdgcn_global_load_lds((gas_ptr)g, (las_ptr)l, 16, 0, 0);
}

// ---------------- fp32 -> bf16 convert ----------------
__global__ __launch_bounds__(256) void cvt_bf16(const float* __restrict__ in,
                                                bf16* __restrict__ out, int n) {
  int idx = (blockIdx.x * 256 + threadIdx.x) * 8;
  if (idx >= n) return;
  f32x4 a = *(const f32x4*)&in[idx];
  f32x4 b = *(const f32x4*)&in[idx + 4];
  bf16x8 o;
#pragma unroll
  for (int j = 0; j < 4; j++) { o[j] = (bf16)a[j]; o[j + 4] = (bf16)b[j]; }
  *(bf16x8*)&out[idx] = o;
}

// ---------------- 128x128 GEMM, C = A @ B^T + bias ----------------
// A [M][K] bf16 row-major, B [N][K] bf16 row-major (both K-contiguous).
// MODE 0: qkv epilogue -> scatter q_s[12][4096][64], k_s[12][4096][64],
//         v_t[12][64][4096] (transposed). MODE 1: fp32 out [M][N].
template <int MODE>
__global__ __launch_bounds__(256) void gemm128(
    const bf16* __restrict__ A, const bf16* __restrict__ B,
    const float* __restrict__ bias, int K, int N,
    bf16* __restrict__ q_s, bf16* __restrict__ k_s, bf16* __restrict__ v_t,
    float* __restrict__ outf) {
  __shared__ __align__(16) bf16 lA[128 * 32];
  __shared__ __align__(16) bf16 lB[128 * 32];
  const int tid = threadIdx.x;
  const int w = tid >> 6, l = tid & 63;
  const int n0 = blockIdx.x * 128, m0 = blockIdx.y * 128;

  f32x4 acc[4][4] = {};

  // staging: 8KB per tile = 8 chunks of 1KB; wave w stages chunks 2w, 2w+1
  const int ch0 = w * 2, ch1 = ch0 + 1;
  const int r0 = ch0 * 16 + (l >> 2), r1 = ch1 * 16 + (l >> 2);
  const int ce = (l & 3) * 8;  // k-element offset of this lane's 16B
  const int mw = (w & 1) * 64, nw = (w >> 1) * 64;

  for (int k0 = 0; k0 < K; k0 += 32) {
    __syncthreads();
    gl_lds16(&A[(size_t)(m0 + r0) * K + k0 + ce], &lA[ch0 * 512]);
    gl_lds16(&A[(size_t)(m0 + r1) * K + k0 + ce], &lA[ch1 * 512]);
    gl_lds16(&B[(size_t)(n0 + r0) * K + k0 + ce], &lB[ch0 * 512]);
    gl_lds16(&B[(size_t)(n0 + r1) * K + k0 + ce], &lB[ch1 * 512]);
    __syncthreads();
    bf16x8 af[4], bfr[4];
#pragma unroll
    for (int i = 0; i < 4; i++)
      af[i] = *(const bf16x8*)&lA[(mw + i * 16 + (l & 15)) * 32 + (l >> 4) * 8];
#pragma unroll
    for (int i = 0; i < 4; i++)
      bfr[i] = *(const bf16x8*)&lB[(nw + i * 16 + (l & 15)) * 32 + (l >> 4) * 8];
#pragma unroll
    for (int mi = 0; mi < 4; mi++)
#pragma unroll
      for (int ni = 0; ni < 4; ni++)
        acc[mi][ni] = mfma16(af[mi], bfr[ni], acc[mi][ni]);
  }

#pragma unroll
  for (int ni = 0; ni < 4; ni++) {
    const int n = n0 + nw + ni * 16 + (l & 15);
    const float bv = bias[n];
#pragma unroll
    for (int mi = 0; mi < 4; mi++) {
#pragma unroll
      for (int i = 0; i < 4; i++) {
        const int m = m0 + mw + mi * 16 + (l >> 4) * 4 + i;
        const float v = acc[mi][ni][i] + bv;
        if (MODE == 0) {
          const int which = n / 768, hn = n % 768;
          const int head = hn >> 6, hd = hn & 63;
          if (which == 0)      q_s[((size_t)head * 4096 + m) * 64 + hd] = (bf16)v;
          else if (which == 1) k_s[((size_t)head * 4096 + m) * 64 + hd] = (bf16)v;
          else                 v_t[((size_t)head * 64 + hd) * 4096 + m] = (bf16)v;
        } else {
          outf[(size_t)m * N + n] = v;
        }
      }
    }
  }
}

// ---------------- rel-pos bias kernels ----------------
// mode 0 (rel_h): block (qh, head): out[head][qh*64+qw][kh] = q[.,qh*64+qw,:] . rph[qh-kh+63,:]
// mode 1 (rel_w): block (qw, head): out[head][qh*64+qw][kw] = q[.,qh*64+qw,:] . rpw[qw-kw+63,:]
__global__ __launch_bounds__(64) void rel_pos_kernel(
    const bf16* __restrict__ q_s, const float* __restrict__ table,
    float* __restrict__ out, int mode) {
  const int l = threadIdx.x;
  const int p = blockIdx.x, head = blockIdx.y;
  const size_t hbase = (size_t)head * 4096 * 64;

  f32x4 acc[4][4] = {};
#pragma unroll
  for (int ks = 0; ks < 2; ks++) {
    bf16x8 af[4], bfr[4];
#pragma unroll
    for (int mi = 0; mi < 4; mi++) {
      const int row = mi * 16 + (l & 15);
      const int s = (mode == 0) ? p * 64 + row : row * 64 + p;
      af[mi] = *(const bf16x8*)&q_s[hbase + (size_t)s * 64 + ks * 32 + (l >> 4) * 8];
    }
#pragma unroll
    for (int ni = 0; ni < 4; ni++) {
      const int col = ni * 16 + (l & 15);
      const float* tp = &table[(size_t)(p - col + 63) * 64 + ks * 32 + (l >> 4) * 8];
      f32x4 t0 = *(const f32x4*)tp;
      f32x4 t1 = *(const f32x4*)(tp + 4);
      bf16x8 bb;
#pragma unroll
      for (int j = 0; j < 4; j++) { bb[j] = (bf16)t0[j]; bb[j + 4] = (bf16)t1[j]; }
      bfr[ni] = bb;
    }
#pragma unroll
    for (int mi = 0; mi < 4; mi++)
#pragma unroll
      for (int ni = 0; ni < 4; ni++)
        acc[mi][ni] = mfma16(af[mi], bfr[ni], acc[mi][ni]);
  }
#pragma unroll
  for (int mi = 0; mi < 4; mi++)
#pragma unroll
    for (int ni = 0; ni < 4; ni++)
#pragma unroll
      for (int i = 0; i < 4; i++) {
        const int row = mi * 16 + (l >> 4) * 4 + i;
        const int col = ni * 16 + (l & 15);
        const int sq = (mode == 0) ? p * 64 + row : row * 64 + p;
        out[hbase + (size_t)sq * 64 + col] = acc[mi][ni][i];
      }
}

// ---------------- flash attention with rel-pos bias ----------------
// Block: (qh, head), 256 threads = 4 waves; wave w owns query rows
// qh*64 + w*16 .. +16. 64 key tiles of 64 keys (tile t == key row kh == t).
// score = 0.125*q.k + bias_h[s_q][t] + bias_w[s_q][kw]
__global__ __launch_bounds__(256) void flash_attn(
    const bf16* __restrict__ q_s, const bf16* __restrict__ k_s,
    const bf16* __restrict__ v_t, const float* __restrict__ bias_h,
    const float* __restrict__ bias_w, bf16* __restrict__ attn_out) {
  __shared__ __align__(16) bf16 lK[64 * 64];   // [key][hd], chunk-swizzled
  __shared__ __align__(16) bf16 lV[64 * 64];   // [hd][key], chunk-swizzled
  __shared__ __align__(16) float lBH[64 * 64]; // [qw][t], linear
  __shared__ __align__(16) bf16 lP[4][16 * 64];// per-wave [q][k], swizzled

  const int tid = threadIdx.x;
  const int w = tid >> 6, l = tid & 63;
  const int qh = blockIdx.x, head = blockIdx.y;
  const size_t hbase = (size_t)head * 4096 * 64;

  // Q fragments (A-operand): row = l&15 within wave strip
  bf16x8 qf[2];
  {
    const size_t s = (size_t)(qh * 64 + w * 16 + (l & 15));
    qf[0] = *(const bf16x8*)&q_s[hbase + s * 64 + (l >> 4) * 8];
    qf[1] = *(const bf16x8*)&q_s[hbase + s * 64 + 32 + (l >> 4) * 8];
  }
  // bias_w fragments, D-layout rows: (l>>4)*4+i
  float bw[4][4];
#pragma unroll
  for (int ni = 0; ni < 4; ni++)
#pragma unroll
    for (int i = 0; i < 4; i++)
      bw[ni][i] = bias_w[hbase +
          (size_t)(qh * 64 + w * 16 + (l >> 4) * 4 + i) * 64 + ni * 16 + (l & 15)];

  // stage bias_h block (contiguous 16KB): chunk = w*4+c, lane gets 16B
#pragma unroll
  for (int c = 0; c < 4; c++) {
    const int ch = w * 4 + c;
    gl_lds16(&bias_h[hbase + (size_t)qh * 4096 + ch * 256 + l * 4], &lBH[ch * 256]);
  }

  f32x4 oacc[4] = {};
  float mrun[4] = {-1e30f, -1e30f, -1e30f, -1e30f};
  float lrun[4] = {0.f, 0.f, 0.f, 0.f};

  // K/V staging geometry: 8KB tile = 8 chunks; wave w stages chunks 2w,2w+1.
  // LDS row = 128B; source 16B-chunk col pre-swizzled with (row&7) so reads
  // at (chunk ^ (row&7)) hit the logical chunk conflict-free.
  const int cb = l & 7;
  const int ch0 = w * 2, ch1 = ch0 + 1;
  const int rk0 = ch0 * 8 + (l >> 3), rk1 = ch1 * 8 + (l >> 3);
  const int sc0 = (cb ^ (rk0 & 7)) * 8, sc1 = (cb ^ (rk1 & 7)) * 8;

  for (int t = 0; t < 64; t++) {
    __syncthreads();
    gl_lds16(&k_s[hbase + (size_t)(t * 64 + rk0) * 64 + sc0], &lK[ch0 * 512]);
    gl_lds16(&k_s[hbase + (size_t)(t * 64 + rk1) * 64 + sc1], &lK[ch1 * 512]);
    gl_lds16(&v_t[hbase + (size_t)rk0 * 4096 + t * 64 + sc0], &lV[ch0 * 512]);
    gl_lds16(&v_t[hbase + (size_t)rk1 * 4096 + t * 64 + sc1], &lV[ch1 * 512]);
    __syncthreads();

    // ---- QK^T ----
    f32x4 sa[4] = {};
#pragma unroll
    for (int ks = 0; ks < 2; ks++)
#pragma unroll
      for (int ni = 0; ni < 4; ni++) {
        const int key = ni * 16 + (l & 15);
        bf16x8 kf = *(const bf16x8*)
            &lK[key * 64 + ((ks * 4 + (l >> 4)) ^ (key & 7)) * 8];
        sa[ni] = mfma16(qf[ks], kf, sa[ni]);
      }

    // ---- scores + online softmax ----
    float bh[4];
#pragma unroll
    for (int i = 0; i < 4; i++)
      bh[i] = lBH[(w * 16 + (l >> 4) * 4 + i) * 64 + t];
    float pr[4][4], rm[4];
#pragma unroll
    for (int i = 0; i < 4; i++) {
#pragma unroll
      for (int ni = 0; ni < 4; ni++)
        pr[ni][i] = sa[ni][i] * 0.125f + bw[ni][i] + bh[i];
      rm[i] = fmaxf(fmaxf(pr[0][i], pr[1][i]), fmaxf(pr[2][i], pr[3][i]));
    }
#pragma unroll
    for (int d = 1; d < 16; d <<= 1)
#pragma unroll
      for (int i = 0; i < 4; i++)
        rm[i] = fmaxf(rm[i], __shfl_xor(rm[i], d, 64));
    float al[4], rs[4];
#pragma unroll
    for (int i = 0; i < 4; i++) {
      const float mn = fmaxf(mrun[i], rm[i]);
      al[i] = __expf(mrun[i] - mn);
      mrun[i] = mn;
      float r = 0.f;
#pragma unroll
      for (int ni = 0; ni < 4; ni++) {
        pr[ni][i] = __expf(pr[ni][i] - mn);
        r += pr[ni][i];
      }
      rs[i] = r;
    }
#pragma unroll
    for (int d = 1; d < 16; d <<= 1)
#pragma unroll
      for (int i = 0; i < 4; i++)
        rs[i] += __shfl_xor(rs[i], d, 64);
#pragma unroll
    for (int i = 0; i < 4; i++)
      lrun[i] = lrun[i] * al[i] + rs[i];
#pragma unroll
    for (int nh = 0; nh < 4; nh++)
#pragma unroll
      for (int i = 0; i < 4; i++)
        oacc[nh][i] *= al[i];

    // ---- P -> LDS (bf16), swizzled [q][k] ----
#pragma unroll
    for (int ni = 0; ni < 4; ni++)
#pragma unroll
      for (int i = 0; i < 4; i++) {
        const int q = (l >> 4) * 4 + i;
        const int k = ni * 16 + (l & 15);
        lP[w][q * 64 + ((k >> 3) ^ (q & 7)) * 8 + (k & 7)] = (bf16)pr[ni][i];
      }

    // ---- PV ----
    bf16x8 pf[2];
#pragma unroll
    for (int ks = 0; ks < 2; ks++)
      pf[ks] = *(const bf16x8*)
          &lP[w][(l & 15) * 64 + ((ks * 4 + (l >> 4)) ^ (l & 7)) * 8];
#pragma unroll
    for (int ks = 0; ks < 2; ks++)
#pragma unroll
      for (int nh = 0; nh < 4; nh++) {
        const int hd = nh * 16 + (l & 15);
        bf16x8 vf = *(const bf16x8*)
            &lV[hd * 64 + ((ks * 4 + (l >> 4)) ^ (hd & 7)) * 8];
        oacc[nh] = mfma16(pf[ks], vf, oacc[nh]);
      }
  }

  // ---- epilogue: O / l, write [s][head*64+hd] bf16 ----
#pragma unroll
  for (int nh = 0; nh < 4; nh++)
#pragma unroll
    for (int i = 0; i < 4; i++) {
      const int sq = qh * 64 + w * 16 + (l >> 4) * 4 + i;
      attn_out[(size_t)sq * 768 + head * 64 + nh * 16 + (l & 15)] =
          (bf16)(oacc[nh][i] / lrun[i]);
    }
}

// ---------------- launch ----------------
extern "C" void kernel_launch(void* const* d_in, const int* in_sizes, int n_in,
                              void* d_out, int out_size, void* d_ws, size_t ws_size,
                              hipStream_t stream) {
  const float* x      = (const float*)d_in[0];
  const float* qkv_w  = (const float*)d_in[1];
  const float* qkv_b  = (const float*)d_in[2];
  const float* proj_w = (const float*)d_in[3];
  const float* proj_b = (const float*)d_in[4];
  const float* rph    = (const float*)d_in[5];
  const float* rpw    = (const float*)d_in[6];

  char* ws = (char*)d_ws;
  bf16*  xb    = (bf16*)(ws);                 //  6.29 MB [4096][768]
  bf16*  wqkv  = (bf16*)(ws + 6291456);       //  3.54 MB [2304][768]
  bf16*  wproj = (bf16*)(ws + 9830400);       //  1.18 MB [768][768]
  bf16*  q_s   = (bf16*)(ws + 11010048);      //  6.29 MB [12][4096][64]
  bf16*  k_s   = (bf16*)(ws + 17301504);      //  6.29 MB [12][4096][64]
  bf16*  v_t   = (bf16*)(ws + 23592960);      //  6.29 MB [12][64][4096]
  bf16*  attno = (bf16*)(ws + 29884416);      //  6.29 MB [4096][768]
  float* bh    = (float*)(ws + 36175872);     // 12.58 MB [12][4096][64]
  float* bwv   = (float*)(ws + 48758784);     // 12.58 MB [12][4096][64]

  cvt_bf16<<<1536, 256, 0, stream>>>(x, xb, 3145728);
  cvt_bf16<<<864, 256, 0, stream>>>(qkv_w, wqkv, 1769472);
  cvt_bf16<<<288, 256, 0, stream>>>(proj_w, wproj, 589824);

  gemm128<0><<<dim3(18, 32), 256, 0, stream>>>(xb, wqkv, qkv_b, 768, 2304,
                                               q_s, k_s, v_t, nullptr);

  rel_pos_kernel<<<dim3(64, 12), 64, 0, stream>>>(q_s, rph, bh, 0);
  rel_pos_kernel<<<dim3(64, 12), 64, 0, stream>>>(q_s, rpw, bwv, 1);

  flash_attn<<<dim3(64, 12), 256, 0, stream>>>(q_s, k_s, v_t, bh, bwv, attno);

  gemm128<1><<<dim3(6, 32), 256, 0, stream>>>(attno, wproj, proj_b, 768, 768,
                                              nullptr, nullptr, nullptr,
                                              (float*)d_out);
}

// Round 2
// 257.273 us; speedup vs baseline: 1.3426x; 1.3426x over previous
//
#include <hip/hip_runtime.h>

// SAM ViT-B global attention, MI355X bf16-MFMA implementation.
// R2: swapped-QK^T flash (in-register softmax, permuted-key lane-local P),
//     exp2-domain softmax + defer-max, double-buffered K/V (1 barrier/tile),
//     rel_h fused into flash prologue, launches merged 8->5.

typedef __bf16 bf16;
typedef __bf16 bf16x8 __attribute__((ext_vector_type(8)));
typedef __bf16 bf16x4 __attribute__((ext_vector_type(4)));
typedef float f32x4 __attribute__((ext_vector_type(4)));

__device__ __forceinline__ f32x4 mfma16(bf16x8 a, bf16x8 b, f32x4 c) {
  return __builtin_amdgcn_mfma_f32_16x16x32_bf16(a, b, c, 0, 0, 0);
}

typedef const __attribute__((address_space(1))) void* gas_ptr;
typedef __attribute__((address_space(3))) void* las_ptr;
__device__ __forceinline__ void gl_lds16(const void* g, void* l) {
  __builtin_amdgcn_global_load_lds((gas_ptr)g, (las_ptr)l, 16, 0, 0);
}

#define L2E 1.4426950408889634f

// ---------------- fp32 -> bf16 convert, 3 tensors in one launch ----------------
__global__ __launch_bounds__(256) void cvt3(
    const float* __restrict__ a, bf16* __restrict__ oa,
    const float* __restrict__ b, bf16* __restrict__ ob,
    const float* __restrict__ c, bf16* __restrict__ oc) {
  // a: 3145728 elems = 1536 blocks; b: 1769472 = 864; c: 589824 = 288
  int blk = blockIdx.x;
  const float* src;
  bf16* dst;
  int base;
  if (blk < 1536)       { src = a; dst = oa; base = blk; }
  else if (blk < 2400)  { src = b; dst = ob; base = blk - 1536; }
  else                  { src = c; dst = oc; base = blk - 2400; }
  int idx = (base * 256 + threadIdx.x) * 8;
  f32x4 x = *(const f32x4*)&src[idx];
  f32x4 y = *(const f32x4*)&src[idx + 4];
  bf16x8 o;
#pragma unroll
  for (int j = 0; j < 4; j++) { o[j] = (bf16)x[j]; o[j + 4] = (bf16)y[j]; }
  *(bf16x8*)&dst[idx] = o;
}

// ---------------- 128x128 GEMM, C = A @ B^T + bias ----------------
template <int MODE>
__global__ __launch_bounds__(256) void gemm128(
    const bf16* __restrict__ A, const bf16* __restrict__ B,
    const float* __restrict__ bias, int K, int N,
    bf16* __restrict__ q_s, bf16* __restrict__ k_s, bf16* __restrict__ v_t,
    float* __restrict__ outf) {
  __shared__ __align__(16) bf16 lA[128 * 32];
  __shared__ __align__(16) bf16 lB[128 * 32];
  const int tid = threadIdx.x;
  const int w = tid >> 6, l = tid & 63;
  const int n0 = blockIdx.x * 128, m0 = blockIdx.y * 128;

  f32x4 acc[4][4] = {};

  const int ch0 = w * 2, ch1 = ch0 + 1;
  const int r0 = ch0 * 16 + (l >> 2), r1 = ch1 * 16 + (l >> 2);
  const int ce = (l & 3) * 8;
  const int mw = (w & 1) * 64, nw = (w >> 1) * 64;

  for (int k0 = 0; k0 < K; k0 += 32) {
    __syncthreads();
    gl_lds16(&A[(size_t)(m0 + r0) * K + k0 + ce], &lA[ch0 * 512]);
    gl_lds16(&A[(size_t)(m0 + r1) * K + k0 + ce], &lA[ch1 * 512]);
    gl_lds16(&B[(size_t)(n0 + r0) * K + k0 + ce], &lB[ch0 * 512]);
    gl_lds16(&B[(size_t)(n0 + r1) * K + k0 + ce], &lB[ch1 * 512]);
    __syncthreads();
    bf16x8 af[4], bfr[4];
#pragma unroll
    for (int i = 0; i < 4; i++)
      af[i] = *(const bf16x8*)&lA[(mw + i * 16 + (l & 15)) * 32 + (l >> 4) * 8];
#pragma unroll
    for (int i = 0; i < 4; i++)
      bfr[i] = *(const bf16x8*)&lB[(nw + i * 16 + (l & 15)) * 32 + (l >> 4) * 8];
#pragma unroll
    for (int mi = 0; mi < 4; mi++)
#pragma unroll
      for (int ni = 0; ni < 4; ni++)
        acc[mi][ni] = mfma16(af[mi], bfr[ni], acc[mi][ni]);
  }

#pragma unroll
  for (int ni = 0; ni < 4; ni++) {
    const int n = n0 + nw + ni * 16 + (l & 15);
    const float bv = bias[n];
#pragma unroll
    for (int mi = 0; mi < 4; mi++) {
#pragma unroll
      for (int i = 0; i < 4; i++) {
        const int m = m0 + mw + mi * 16 + (l >> 4) * 4 + i;
        const float v = acc[mi][ni][i] + bv;
        if (MODE == 0) {
          const int which = n / 768, hn = n % 768;
          const int head = hn >> 6, hd = hn & 63;
          if (which == 0)      q_s[((size_t)head * 4096 + m) * 64 + hd] = (bf16)v;
          else if (which == 1) k_s[((size_t)head * 4096 + m) * 64 + hd] = (bf16)v;
          else                 v_t[((size_t)head * 64 + hd) * 4096 + m] = (bf16)v;
        } else {
          outf[(size_t)m * N + n] = v;
        }
      }
    }
  }
}

// ---------------- rel_w bias kernel (rel_h is fused into flash) ----------------
// block (qw=p, head): out[head][qh*64+p][kw] = q[., qh*64+p, :] . rpw[p-kw+63, :]
__global__ __launch_bounds__(64) void rel_pos_w(
    const bf16* __restrict__ q_s, const float* __restrict__ table,
    float* __restrict__ out) {
  const int l = threadIdx.x;
  const int p = blockIdx.x, head = blockIdx.y;
  const size_t hbase = (size_t)head * 4096 * 64;

  f32x4 acc[4][4] = {};
#pragma unroll
  for (int ks = 0; ks < 2; ks++) {
    bf16x8 af[4], bfr[4];
#pragma unroll
    for (int mi = 0; mi < 4; mi++) {
      const int row = mi * 16 + (l & 15);
      const int s = row * 64 + p;  // qh = row, qw = p
      af[mi] = *(const bf16x8*)&q_s[hbase + (size_t)s * 64 + ks * 32 + (l >> 4) * 8];
    }
#pragma unroll
    for (int ni = 0; ni < 4; ni++) {
      const int col = ni * 16 + (l & 15);
      const float* tp = &table[(size_t)(p - col + 63) * 64 + ks * 32 + (l >> 4) * 8];
      f32x4 t0 = *(const f32x4*)tp;
      f32x4 t1 = *(const f32x4*)(tp + 4);
      bf16x8 bb;
#pragma unroll
      for (int j = 0; j < 4; j++) { bb[j] = (bf16)t0[j]; bb[j + 4] = (bf16)t1[j]; }
      bfr[ni] = bb;
    }
#pragma unroll
    for (int mi = 0; mi < 4; mi++)
#pragma unroll
      for (int ni = 0; ni < 4; ni++)
        acc[mi][ni] = mfma16(af[mi], bfr[ni], acc[mi][ni]);
  }
#pragma unroll
  for (int mi = 0; mi < 4; mi++)
#pragma unroll
    for (int ni = 0; ni < 4; ni++)
#pragma unroll
      for (int i = 0; i < 4; i++) {
        const int row = mi * 16 + (l >> 4) * 4 + i;
        const int col = ni * 16 + (l & 15);
        const int sq = row * 64 + p;
        out[hbase + (size_t)sq * 64 + col] = acc[mi][ni][i];
      }
}

// ---------------- flash attention, swapped-QK^T in-register softmax ----------
// Block (qh, head), 4 waves; wave w owns queries qh*64 + w*16 .. +16.
// Lane owns query q = l&15 of its wave strip; its 16 S-values per 64-key tile
// are keys key(ni,g,i) = (ni>>1)*32 + g*8 + (ni&1)*4 + i  (g = l>>4), which is
// exactly the PV B-fragment it needs -> P never leaves the lane.
__global__ __launch_bounds__(256) void flash_attn(
    const bf16* __restrict__ q_s, const bf16* __restrict__ k_s,
    const bf16* __restrict__ v_t, const float* __restrict__ rph,
    const float* __restrict__ bias_w, bf16* __restrict__ attn_out) {
  __shared__ __align__(16) bf16 lK[2][64 * 64];  // [key][hd], f_K-swizzled
  __shared__ __align__(16) bf16 lV[2][64 * 64];  // [hd][key], f_V-swizzled
  __shared__ float lBH[64 * 65];                 // [q][t], padded (+1)

  const int tid = threadIdx.x;
  const int w = tid >> 6, l = tid & 63;
  const int g = l >> 4, q16 = l & 15;
  const int qh = blockIdx.x, head = blockIdx.y;
  const size_t hbase = (size_t)head * 4096 * 64;
  const int qloc = w * 16 + q16;
  const size_t sq = (size_t)qh * 64 + qloc;

  // Q fragments (B-operand: col = q, k-slice = g*8)
  bf16x8 qf[2];
  qf[0] = *(const bf16x8*)&q_s[hbase + sq * 64 + g * 8];
  qf[1] = *(const bf16x8*)&q_s[hbase + sq * 64 + 32 + g * 8];

  // staging geometry (wave w stages chunks 2w,2w+1; chunk = 8 LDS rows)
  const int cb = l & 7;
  const int ch0 = w * 2, ch1 = ch0 + 1;
  const int rk0 = ch0 * 8 + (l >> 3), rk1 = ch1 * 8 + (l >> 3);
  const int fk0 = ((rk0 >> 3) & 3) * 2 + (rk0 & 1);
  const int fk1 = ((rk1 >> 3) & 3) * 2 + (rk1 & 1);
  const int skc0 = (cb ^ fk0) * 8, skc1 = (cb ^ fk1) * 8;
  const int svc0 = (cb ^ (rk0 & 7)) * 8, svc1 = (cb ^ (rk1 & 7)) * 8;

#define STAGE(buf, t)                                                          \
  do {                                                                         \
    gl_lds16(&k_s[hbase + (size_t)((t) * 64 + rk0) * 64 + skc0],               \
             &lK[buf][ch0 * 512]);                                             \
    gl_lds16(&k_s[hbase + (size_t)((t) * 64 + rk1) * 64 + skc1],               \
             &lK[buf][ch1 * 512]);                                             \
    gl_lds16(&v_t[hbase + (size_t)rk0 * 4096 + (t) * 64 + svc0],               \
             &lV[buf][ch0 * 512]);                                             \
    gl_lds16(&v_t[hbase + (size_t)rk1 * 4096 + (t) * 64 + svc1],               \
             &lV[buf][ch1 * 512]);                                             \
  } while (0)

  STAGE(0, 0);

  // fused rel_h: lBH[q][t] = Q[sq] . rph[qh - t + 63]
  {
    f32x4 abh[4] = {};
#pragma unroll
    for (int ks = 0; ks < 2; ks++)
#pragma unroll
      for (int ni = 0; ni < 4; ni++) {
        const int t = ni * 16 + q16;  // A-row = l&15
        const float* tp = &rph[(size_t)(qh + 63 - t) * 64 + ks * 32 + g * 8];
        f32x4 t0 = *(const f32x4*)tp;
        f32x4 t1 = *(const f32x4*)(tp + 4);
        bf16x8 rf;
#pragma unroll
        for (int j = 0; j < 4; j++) { rf[j] = (bf16)t0[j]; rf[j + 4] = (bf16)t1[j]; }
        abh[ni] = mfma16(rf, qf[ks], abh[ni]);
      }
#pragma unroll
    for (int ni = 0; ni < 4; ni++)
#pragma unroll
      for (int i = 0; i < 4; i++)
        lBH[qloc * 65 + ni * 16 + g * 4 + i] = abh[ni][i];
  }

  // rel_w bias, exp2 domain, indexed by this lane's permuted keys
  float c2[4][4];
#pragma unroll
  for (int ni = 0; ni < 4; ni++)
#pragma unroll
    for (int i = 0; i < 4; i++) {
      const int kw = (ni >> 1) * 32 + g * 8 + (ni & 1) * 4 + i;
      c2[ni][i] = bias_w[hbase + sq * 64 + kw] * L2E;
    }

  f32x4 oacc[4] = {};
  float mrun = -1e30f, lrun = 0.f;
  const float SC2 = 0.125f * L2E;

  __syncthreads();

  int cur = 0;
  for (int t = 0; t < 64; t++) {
    STAGE(cur ^ 1, (t + 1 < 64) ? t + 1 : 63);

    // ---- QK^T (A = K rows in permuted order, B = Q) ----
    f32x4 sa[4] = {};
#pragma unroll
    for (int ks = 0; ks < 2; ks++)
#pragma unroll
      for (int ni = 0; ni < 4; ni++) {
        const int key =
            (ni >> 1) * 32 + ((l & 15) >> 2) * 8 + (ni & 1) * 4 + (l & 3);
        const int fk = ((key >> 3) & 3) * 2 + (key & 1);
        bf16x8 kf =
            *(const bf16x8*)&lK[cur][key * 64 + ((ks * 4 + g) ^ fk) * 8];
        sa[ni] = mfma16(kf, qf[ks], sa[ni]);
      }

    // ---- softmax (lane-local row) ----
    const float bh2 = lBH[qloc * 65 + t] * L2E;
    float p[4][4];
    float smax = -1e30f;
#pragma unroll
    for (int ni = 0; ni < 4; ni++)
#pragma unroll
      for (int i = 0; i < 4; i++) {
        p[ni][i] = sa[ni][i] * SC2 + c2[ni][i];
        smax = fmaxf(smax, p[ni][i]);
      }
    smax = fmaxf(smax, __shfl_xor(smax, 16, 64));
    smax = fmaxf(smax, __shfl_xor(smax, 32, 64));
    const float rmf = smax + bh2;

    if (!__all(rmf - mrun <= 8.f)) {  // defer-max: rescale only on real growth
      const float mn = fmaxf(mrun, rmf);
      const float al = __builtin_amdgcn_exp2f(mrun - mn);
      mrun = mn;
      lrun *= al;
#pragma unroll
      for (int nh = 0; nh < 4; nh++)
#pragma unroll
        for (int i = 0; i < 4; i++) oacc[nh][i] *= al;
    }

    const float d = bh2 - mrun;
    float rs = 0.f;
#pragma unroll
    for (int ni = 0; ni < 4; ni++)
#pragma unroll
      for (int i = 0; i < 4; i++) {
        p[ni][i] = __builtin_amdgcn_exp2f(p[ni][i] + d);
        rs += p[ni][i];
      }
    rs += __shfl_xor(rs, 16, 64);
    rs += __shfl_xor(rs, 32, 64);
    lrun += rs;

    // ---- P -> PV B-fragments, fully lane-local ----
    bf16x8 pb[2];
#pragma unroll
    for (int ks = 0; ks < 2; ks++)
#pragma unroll
      for (int j = 0; j < 8; j++)
        pb[ks][j] = (bf16)p[2 * ks + (j >> 2)][j & 3];

    // ---- PV (A = V^T rows = hd, B = P) ----
#pragma unroll
    for (int ks = 0; ks < 2; ks++)
#pragma unroll
      for (int nh = 0; nh < 4; nh++) {
        const int hd = nh * 16 + q16;
        bf16x8 vf =
            *(const bf16x8*)&lV[cur][hd * 64 + ((ks * 4 + g) ^ (hd & 7)) * 8];
        oacc[nh] = mfma16(vf, pb[ks], oacc[nh]);
      }

    __syncthreads();
    cur ^= 1;
  }
#undef STAGE

  // ---- epilogue: lane owns one q row, 16 hd values ----
  const float inv = 1.0f / lrun;
#pragma unroll
  for (int nh = 0; nh < 4; nh++) {
    bf16x4 ov;
#pragma unroll
    for (int i = 0; i < 4; i++) ov[i] = (bf16)(oacc[nh][i] * inv);
    *(bf16x4*)&attn_out[sq * 768 + head * 64 + nh * 16 + g * 4] = ov;
  }
}

// ---------------- launch ----------------
extern "C" void kernel_launch(void* const* d_in, const int* in_sizes, int n_in,
                              void* d_out, int out_size, void* d_ws, size_t ws_size,
                              hipStream_t stream) {
  const float* x      = (const float*)d_in[0];
  const float* qkv_w  = (const float*)d_in[1];
  const float* qkv_b  = (const float*)d_in[2];
  const float* proj_w = (const float*)d_in[3];
  const float* proj_b = (const float*)d_in[4];
  const float* rph    = (const float*)d_in[5];
  const float* rpw    = (const float*)d_in[6];

  char* ws = (char*)d_ws;
  bf16*  xb    = (bf16*)(ws);                 //  6.29 MB [4096][768]
  bf16*  wqkv  = (bf16*)(ws + 6291456);       //  3.54 MB [2304][768]
  bf16*  wproj = (bf16*)(ws + 9830400);       //  1.18 MB [768][768]
  bf16*  q_s   = (bf16*)(ws + 11010048);      //  6.29 MB [12][4096][64]
  bf16*  k_s   = (bf16*)(ws + 17301504);      //  6.29 MB [12][4096][64]
  bf16*  v_t   = (bf16*)(ws + 23592960);      //  6.29 MB [12][64][4096]
  bf16*  attno = (bf16*)(ws + 29884416);      //  6.29 MB [4096][768]
  float* bwv   = (float*)(ws + 36175872);     // 12.58 MB [12][4096][64]

  cvt3<<<2688, 256, 0, stream>>>(x, xb, qkv_w, wqkv, proj_w, wproj);

  gemm128<0><<<dim3(18, 32), 256, 0, stream>>>(xb, wqkv, qkv_b, 768, 2304,
                                               q_s, k_s, v_t, nullptr);

  rel_pos_w<<<dim3(64, 12), 64, 0, stream>>>(q_s, rpw, bwv);

  flash_attn<<<dim3(64, 12), 256, 0, stream>>>(q_s, k_s, v_t, rph, bwv, attno);

  gemm128<1><<<dim3(6, 32), 256, 0, stream>>>(attno, wproj, proj_b, 768, 768,
                                              nullptr, nullptr, nullptr,
                                              (float*)d_out);
}